// Round 1
// baseline (199.707 us; speedup 1.0000x reference)
//
#include <hip/hip_runtime.h>

// out[i] = sin(a_i) * sin(b_i), input interleaved (a,b) pairs, fp32.
// Memory-bound: 192 MiB traffic/call -> ~30us floor at 6.3 TB/s.
// Each thread: one float4 load = 2 rows, one float2 store = 2 outputs.
__global__ __launch_bounds__(256) void sinprod_kernel(
    const float4* __restrict__ in, float2* __restrict__ out, int n4) {
    int i = blockIdx.x * blockDim.x + threadIdx.x;
    if (i < n4) {
        float4 v = in[i];
        float2 o;
        o.x = __sinf(v.x) * __sinf(v.y);
        o.y = __sinf(v.z) * __sinf(v.w);
        out[i] = o;
    }
}

extern "C" void kernel_launch(void* const* d_in, const int* in_sizes, int n_in,
                              void* d_out, int out_size, void* d_ws, size_t ws_size,
                              hipStream_t stream) {
    const float4* in = (const float4*)d_in[0];
    float2* out = (float2*)d_out;
    // out_size = number of rows N; each thread handles 2 rows.
    int n4 = out_size / 2;  // 8,388,608 float4 loads
    int block = 256;
    int grid = (n4 + block - 1) / block;
    sinprod_kernel<<<grid, block, 0, stream>>>(in, out, n4);
}

// Round 3
// 194.454 us; speedup vs baseline: 1.0270x; 1.0270x over previous
//
#include <hip/hip_runtime.h>

// out[i] = sin(a_i) * sin(b_i), input interleaved (a,b) pairs, fp32.
// Memory-bound streaming: 128 MiB read + 64 MiB write per call -> ~30us floor
// at 6.3 TB/s. Zero reuse -> nontemporal loads/stores (skip L2 retention).
// Native ext_vector types: __builtin_nontemporal_* rejects HIP_vector_type.
typedef float vfloat4 __attribute__((ext_vector_type(4)));
typedef float vfloat2 __attribute__((ext_vector_type(2)));

__global__ __launch_bounds__(256) void sinprod_kernel(
    const vfloat4* __restrict__ in, vfloat2* __restrict__ out, int n4) {
    int i0 = blockIdx.x * (blockDim.x * 2) + threadIdx.x;
    int i1 = i0 + blockDim.x;
    if (i1 < n4) {
        vfloat4 v0 = __builtin_nontemporal_load(&in[i0]);
        vfloat4 v1 = __builtin_nontemporal_load(&in[i1]);
        vfloat2 o0, o1;
        o0.x = __sinf(v0.x) * __sinf(v0.y);
        o0.y = __sinf(v0.z) * __sinf(v0.w);
        o1.x = __sinf(v1.x) * __sinf(v1.y);
        o1.y = __sinf(v1.z) * __sinf(v1.w);
        __builtin_nontemporal_store(o0, &out[i0]);
        __builtin_nontemporal_store(o1, &out[i1]);
    }
}

extern "C" void kernel_launch(void* const* d_in, const int* in_sizes, int n_in,
                              void* d_out, int out_size, void* d_ws, size_t ws_size,
                              hipStream_t stream) {
    const vfloat4* in = (const vfloat4*)d_in[0];
    vfloat2* out = (vfloat2*)d_out;
    int n4 = out_size / 2;          // 8,388,608 float4 rows-pairs
    int block = 256;
    int grid = n4 / (block * 2);    // 16384 blocks, exact (n4 % 512 == 0)
    sinprod_kernel<<<grid, block, 0, stream>>>(in, out, n4);
}